// Round 2
// baseline (345.050 us; speedup 1.0000x reference)
//
#include <hip/hip_runtime.h>
#include <hip/hip_bf16.h>
#include <stdint.h>

#define N_TOK 8192
#define DIN   1024
#define DOUT  1024
#define HID   1024
#define NE    8
#define CAP   0.8f   // 1 - EPS

typedef __attribute__((ext_vector_type(8))) short short8;
typedef __attribute__((ext_vector_type(4))) float floatx4;

__device__ __forceinline__ void async_load16(const void* g, void* l) {
  __builtin_amdgcn_global_load_lds(
      (const __attribute__((address_space(1))) void*)g,
      (__attribute__((address_space(3))) void*)l,
      16, 0, 0);
}

__device__ __forceinline__ unsigned short bf16_bits(float f) {
  return __builtin_bit_cast(unsigned short, __float2bfloat16(f));
}

// ---------------------------------------------------------------------------
// Zero-fill d_out (poisoned 0xAA each call).
// ---------------------------------------------------------------------------
__global__ __launch_bounds__(256) void zero_kernel(float4* __restrict__ out4, int n4) {
  const int stride = gridDim.x * 256;
  for (int i = blockIdx.x * 256 + threadIdx.x; i < n4; i += stride)
    out4[i] = (float4){0.f, 0.f, 0.f, 0.f};
}

// ---------------------------------------------------------------------------
// Selector: logits = x @ Wsel + bsel ; softmax ; capped-cumsum sparse weights
// (gather-with-order per torch.gather semantics). Emits x as bf16 + sw.
// ---------------------------------------------------------------------------
__global__ __launch_bounds__(256) void selector_kernel(
    const float* __restrict__ x, const float* __restrict__ Wsel,
    const float* __restrict__ bsel,
    __hip_bfloat16* __restrict__ x_bf, float* __restrict__ sw)
{
  const int lane = threadIdx.x & 63;
  const int wave = threadIdx.x >> 6;
  const int n = blockIdx.x * 4 + wave;
  const float4* xr4 = (const float4*)(x + (size_t)n * DIN);
  ushort4* xb4 = (ushort4*)(x_bf + (size_t)n * DIN);

  float acc[8];
#pragma unroll
  for (int e = 0; e < 8; e++) acc[e] = 0.f;

#pragma unroll
  for (int i = 0; i < 4; i++) {
    const int d4 = lane + i * 64;          // float4 index; covers dims 4*d4..4*d4+3
    const float4 xv = xr4[d4];
    ushort4 p;
    p.x = bf16_bits(xv.x);
    p.y = bf16_bits(xv.y);
    p.z = bf16_bits(xv.z);
    p.w = bf16_bits(xv.w);
    xb4[d4] = p;
    const float xs[4] = {xv.x, xv.y, xv.z, xv.w};
#pragma unroll
    for (int q = 0; q < 4; q++) {
      const int d = d4 * 4 + q;
      const float4* wr = (const float4*)(Wsel + d * 8);
      const float4 wlo = wr[0], whi = wr[1];
      const float xv1 = xs[q];
      acc[0] += xv1 * wlo.x; acc[1] += xv1 * wlo.y;
      acc[2] += xv1 * wlo.z; acc[3] += xv1 * wlo.w;
      acc[4] += xv1 * whi.x; acc[5] += xv1 * whi.y;
      acc[6] += xv1 * whi.z; acc[7] += xv1 * whi.w;
    }
  }
#pragma unroll
  for (int off = 32; off >= 1; off >>= 1)
#pragma unroll
    for (int e = 0; e < 8; e++) acc[e] += __shfl_xor(acc[e], off);

  if (lane == 0) {
    float w[8];
    float mx = -1e30f;
#pragma unroll
    for (int e = 0; e < 8; e++) { w[e] = acc[e] + bsel[e]; mx = fmaxf(mx, w[e]); }
    float s = 0.f;
#pragma unroll
    for (int e = 0; e < 8; e++) { w[e] = expf(w[e] - mx); s += w[e]; }
    const float inv = 1.f / s;
#pragma unroll
    for (int e = 0; e < 8; e++) w[e] *= inv;

    // stable descending argsort (insertion sort; strict < keeps ties stable)
    float wsrt[8]; int ord[8];
    for (int k = 0; k < 8; k++) {
      const float v = w[k];
      int j = k;
      while (j > 0 && wsrt[j - 1] < v) { wsrt[j] = wsrt[j - 1]; ord[j] = ord[j - 1]; j--; }
      wsrt[j] = v; ord[j] = k;
    }
    // capped cumulative sparse weights (sorted order)
    float cum = 0.f, sws[8];
    for (int k = 0; k < 8; k++) {
      cum += wsrt[k];
      const float capped = fminf(cum, CAP);
      sws[k] = fmaxf(capped - cum + wsrt[k], 0.f);
    }
    // faithful to torch.gather(sparse_weight, 1, index): sw[j] = sws[ord[j]]
    for (int j = 0; j < 8; j++) sw[(size_t)n * 8 + j] = sws[ord[j]];
  }
}

// ---------------------------------------------------------------------------
// Per-expert token compaction with ZERO global atomics.
// grid = NE blocks; 1024 threads = 16 waves; 8 chunks of 1024 tokens.
// ---------------------------------------------------------------------------
__global__ __launch_bounds__(1024) void compact_kernel(
    const float* __restrict__ sw, int* __restrict__ idx, int* __restrict__ cnt)
{
  const int e = blockIdx.x;
  const int t = threadIdx.x;
  const int lane = t & 63;
  const int wv = t >> 6;
  __shared__ int wave_base[16];
  __shared__ int chunk_total;
  int base = 0;
#pragma unroll
  for (int c = 0; c < 8; c++) {
    const int tok = c * 1024 + t;
    const bool act = sw[(size_t)tok * 8 + e] > 0.f;
    const unsigned long long m = __ballot(act);
    const int before = __popcll(m & ((1ull << lane) - 1ull));
    if (lane == 0) wave_base[wv] = __popcll(m);
    __syncthreads();
    if (t == 0) {
      int s = 0;
      for (int w = 0; w < 16; w++) { const int v = wave_base[w]; wave_base[w] = s; s += v; }
      chunk_total = s;
    }
    __syncthreads();
    if (act) idx[e * N_TOK + base + wave_base[wv] + before] = tok;
    base += chunk_total;
    __syncthreads();   // protect wave_base/chunk_total before next chunk
  }
  if (t == 0) cnt[e] = base;
}

// ---------------------------------------------------------------------------
// W1[e][k][n] fp32 -> W1t[e][n][k] bf16 ; W2[e][h][o] fp32 -> W2t[e][o][h] bf16
// ---------------------------------------------------------------------------
__global__ __launch_bounds__(256) void convert_weights_kernel(
    const float* __restrict__ W1, const float* __restrict__ W2,
    __hip_bfloat16* __restrict__ W1t, __hip_bfloat16* __restrict__ W2t)
{
  __shared__ float tile[32][33];
  const int z = blockIdx.z;
  const float* src = (z & 8) ? W2 : W1;
  __hip_bfloat16* dst = (z & 8) ? W2t : W1t;
  const int e = z & 7;
  src += (size_t)e * 1024 * 1024;
  dst += (size_t)e * 1024 * 1024;
  const int R = blockIdx.y * 32, C = blockIdx.x * 32;
  const int c = threadIdx.x & 31, r0 = threadIdx.x >> 5;
#pragma unroll
  for (int p = 0; p < 4; p++) {
    const int r = r0 + p * 8;
    tile[r][c] = src[(size_t)(R + r) * 1024 + C + c];
  }
  __syncthreads();
#pragma unroll
  for (int p = 0; p < 4; p++) {
    const int r = r0 + p * 8;
    dst[(size_t)(C + r) * 1024 + R + c] = __float2bfloat16(tile[c][r]);
  }
}

// ---------------------------------------------------------------------------
// Compacted per-expert GEMM, 128x128 tile, BK=32.
// TRIPLE-buffered LDS + COUNTED vmcnt (AITER pattern, never vmcnt(0) in the
// main loop) + raw s_barrier (no vmcnt(0) drain — __syncthreads' implicit
// drain was the round-1 bottleneck). Loads for tile t stay in flight ~2 full
// iterations (~900 cy) before being awaited with vmcnt(8).
// Barrier 1 (post-vmcnt): all waves' tile-t loads landed in LDS.
// Barrier 2 (post-MFMA): all waves done reading buf[t%3] before any wave
// stages tile t+3 into that same buffer next iteration.
// sched_barrier(0) after each s_barrier + "memory" clobber on the vmcnt asm
// pin ds_read/global_load_lds motion (guide rule 18 discipline).
// MODE 0 (FC1): A = gather(x_bf, idx[e]);  hpool[e] = bf16(relu(A W1t^T + b1))
// MODE 1 (FC2): A = hpool[e];  out[idx[e][m]] += sw * (A W2t^T + b2)  (atomic)
// ---------------------------------------------------------------------------
#define BUFO (128 * 32)   // elements per LDS buffer (8 KB bf16)

template <int MODE>
__global__ __launch_bounds__(256, 3) void moe_gemm(
    const __hip_bfloat16* __restrict__ x_bf,
    __hip_bfloat16* __restrict__ hpool,
    const __hip_bfloat16* __restrict__ Wt,
    const float* __restrict__ biasAll,
    const float* __restrict__ sw,
    const int* __restrict__ idx, const int* __restrict__ cnt,
    float* __restrict__ out)
{
  const int e = blockIdx.z;
  const int count = cnt[e];
  const int m0 = blockIdx.y * 128;
  if (m0 >= count) return;
  const int n0 = blockIdx.x * 128;

  __shared__ __align__(16) __hip_bfloat16 sA[3 * BUFO];
  __shared__ __align__(16) __hip_bfloat16 sB[3 * BUFO];
  const int t = threadIdx.x;
  const int lane = t & 63;
  const int wave = t >> 6;
  const int wm = (wave & 1) * 64;
  const int wn = (wave >> 1) * 64;
  const int* idx_e = idx + e * N_TOK;
  const float* bias = biasAll + e * 1024;

  floatx4 acc[4][4];
#pragma unroll
  for (int i = 0; i < 4; i++)
#pragma unroll
    for (int j = 0; j < 4; j++) acc[i][j] = (floatx4){0.f, 0.f, 0.f, 0.f};

  // staging addresses: thread t loads 16B for rows sr and sr+64
  const int sr = t >> 2;
  const int sc = (t & 3) * 8;
  const __hip_bfloat16* Ag0;
  const __hip_bfloat16* Ag1;
  if (MODE == 0) {
    const int t0 = idx_e[min(m0 + sr, count - 1)];       // clamp tail (valid rows)
    const int t1 = idx_e[min(m0 + sr + 64, count - 1)];
    Ag0 = x_bf + (size_t)t0 * 1024 + sc;
    Ag1 = x_bf + (size_t)t1 * 1024 + sc;
  } else {
    const __hip_bfloat16* hp = hpool + (size_t)e * N_TOK * 1024;
    Ag0 = hp + (size_t)(m0 + sr) * 1024 + sc;            // tail reads scratch: finite
    Ag1 = hp + (size_t)(m0 + sr + 64) * 1024 + sc;
  }
  const __hip_bfloat16* Bg = Wt + (size_t)e * 1024 * 1024 + (size_t)(n0 + sr) * 1024 + sc;
  __hip_bfloat16* lA = &sA[sr * 32 + sc];
  __hip_bfloat16* lB = &sB[sr * 32 + sc];

  const int rf = lane & 15;
  const int k8 = (lane >> 4) * 8;
  const int roA = (wm + rf) * 32 + k8;
  const int roB = (wn + rf) * 32 + k8;

  // stage K-tile KT (byte col offset KT*32) into buffer WB
#define STAGE(KT, WB)                                                           \
  {                                                                             \
    const int kof = (KT) * 32;                                                  \
    async_load16(Ag0 + kof, lA + (WB) * BUFO);                                  \
    async_load16(Ag1 + kof, lA + (WB) * BUFO + 64 * 32);                        \
    async_load16(Bg + kof, lB + (WB) * BUFO);                                   \
    async_load16(Bg + (size_t)64 * 1024 + kof, lB + (WB) * BUFO + 64 * 32);     \
  }

  // compute tile resident in buffer RB (after WAIT + barrier)
#define GSTEP(RB, WAIT)                                                         \
  {                                                                             \
    asm volatile("s_waitcnt " WAIT ::: "memory");                               \
    __builtin_amdgcn_s_barrier();                                               \
    __builtin_amdgcn_sched_barrier(0);                                          \
    const __hip_bfloat16* pA = &sA[(RB) * BUFO + roA];                          \
    const __hip_bfloat16* pB = &sB[(RB) * BUFO + roB];                          \
    short8 aF[4], bF[4];                                                        \
    _Pragma("unroll")                                                           \
    for (int i = 0; i < 4; i++) aF[i] = *(const short8*)(pA + i * 16 * 32);     \
    _Pragma("unroll")                                                           \
    for (int j = 0; j < 4; j++) bF[j] = *(const short8*)(pB + j * 16 * 32);     \
    _Pragma("unroll")                                                           \
    for (int i = 0; i < 4; i++)                                                 \
      _Pragma("unroll")                                                         \
      for (int j = 0; j < 4; j++)                                               \
        acc[i][j] = __builtin_amdgcn_mfma_f32_16x16x32_bf16(aF[i], bF[j],       \
                                                            acc[i][j], 0, 0, 0);\
    __builtin_amdgcn_s_barrier();                                               \
    __builtin_amdgcn_sched_barrier(0);                                          \
  }

  // prologue: tiles 0,1 in flight (8 outstanding load instrs per wave)
  STAGE(0, 0);
  STAGE(1, 1);

  // main loop: 30 tiles, unrolled x3 for compile-time buffer indices.
  // Each step: stage t+2 (12 outstanding), vmcnt(8) -> tile t landed.
#pragma unroll 1
  for (int kt = 0; kt < 30; kt += 3) {
    STAGE(kt + 2, 2);
    GSTEP(0, "vmcnt(8)");
    STAGE(kt + 3, 0);
    GSTEP(1, "vmcnt(8)");
    STAGE(kt + 4, 1);
    GSTEP(2, "vmcnt(8)");
  }
  // tails: tiles 30 (buf 0) and 31 (buf 1), nothing left to stage.
  GSTEP(0, "vmcnt(4)");
  GSTEP(1, "vmcnt(0)");
#undef GSTEP
#undef STAGE

  // epilogue: C/D layout col = lane&15, row = (lane>>4)*4 + reg
  const int quad = lane >> 4;
  const int cn = lane & 15;
#pragma unroll
  for (int i = 0; i < 4; i++) {
#pragma unroll
    for (int r = 0; r < 4; r++) {
      const int gm = m0 + wm + i * 16 + quad * 4 + r;
      if (gm >= count) continue;
      int tok = 0; float swv = 0.f;
      if (MODE == 1) {
        tok = idx_e[gm];
        swv = sw[tok * 8 + e];
      }
#pragma unroll
      for (int j = 0; j < 4; j++) {
        const int gn = n0 + wn + j * 16 + cn;
        const float v = acc[i][j][r] + bias[gn];
        if (MODE == 0) {
          hpool[((size_t)e * N_TOK + gm) * 1024 + gn] = __float2bfloat16(fmaxf(v, 0.f));
        } else {
          unsafeAtomicAdd(&out[(size_t)tok * 1024 + gn], swv * v);
        }
      }
    }
  }
}

// NOTE on main-loop staging: STAGE(kt+3) for kt=27 stages tile 30, STAGE(kt+4)
// stages tile 31 — max staged tile index is 31 (= last), never out of range.

// ---------------------------------------------------------------------------
extern "C" void kernel_launch(void* const* d_in, const int* in_sizes, int n_in,
                              void* d_out, int out_size, void* d_ws, size_t ws_size,
                              hipStream_t stream) {
  const float* x    = (const float*)d_in[0];
  const float* Wsel = (const float*)d_in[1];
  const float* bsel = (const float*)d_in[2];
  const float* W1   = (const float*)d_in[3];
  const float* b1   = (const float*)d_in[4];
  const float* W2   = (const float*)d_in[5];
  const float* b2   = (const float*)d_in[6];
  float* out = (float*)d_out;

  char* ws = (char*)d_ws;
  __hip_bfloat16* x_bf = (__hip_bfloat16*)ws; ws += (size_t)N_TOK * DIN * 2;
  __hip_bfloat16* W1t  = (__hip_bfloat16*)ws; ws += (size_t)NE * DIN * HID * 2;
  __hip_bfloat16* W2t  = (__hip_bfloat16*)ws; ws += (size_t)NE * HID * DOUT * 2;
  float* sw            = (float*)ws;          ws += (size_t)N_TOK * NE * 4;
  int* idx             = (int*)ws;            ws += (size_t)NE * N_TOK * 4;
  int* cnt             = (int*)ws;            ws += 256;
  __hip_bfloat16* hpool = (__hip_bfloat16*)ws;  // NE*N_TOK*HID*2 = 134 MB

  zero_kernel<<<1024, 256, 0, stream>>>((float4*)out, N_TOK * DOUT / 4);
  selector_kernel<<<N_TOK / 4, 256, 0, stream>>>(x, Wsel, bsel, x_bf, sw);
  compact_kernel<<<NE, 1024, 0, stream>>>(sw, idx, cnt);
  convert_weights_kernel<<<dim3(32, 32, 16), 256, 0, stream>>>(W1, W2, W1t, W2t);

  moe_gemm<0><<<dim3(HID / 128, N_TOK / 128, NE), 256, 0, stream>>>(
      x_bf, hpool, W1t, b1, sw, idx, cnt, out);
  moe_gemm<1><<<dim3(DOUT / 128, N_TOK / 128, NE), 256, 0, stream>>>(
      x_bf, hpool, W2t, b2, sw, idx, cnt, out);
}

// Round 3
// 321.950 us; speedup vs baseline: 1.0718x; 1.0718x over previous
//
#include <hip/hip_runtime.h>
#include <hip/hip_bf16.h>
#include <stdint.h>

#define N_TOK 8192
#define DIN   1024
#define DOUT  1024
#define HID   1024
#define NE    8
#define CAP   0.8f   // 1 - EPS

typedef __attribute__((ext_vector_type(8))) short short8;
typedef __attribute__((ext_vector_type(4))) float floatx4;

__device__ __forceinline__ void async_load16(const void* g, void* l) {
  __builtin_amdgcn_global_load_lds(
      (const __attribute__((address_space(1))) void*)g,
      (__attribute__((address_space(3))) void*)l,
      16, 0, 0);
}

__device__ __forceinline__ unsigned short bf16_bits(float f) {
  return __builtin_bit_cast(unsigned short, __float2bfloat16(f));
}

// ---------------------------------------------------------------------------
// Selector: logits = x @ Wsel + bsel ; softmax ; capped-cumsum sparse weights.
// Emits x as bf16 + sw. ALSO zero-fills d_out (fused former zero_kernel:
// 2048 blocks x 1024 float4 = 8192*1024 floats).
// ---------------------------------------------------------------------------
__global__ __launch_bounds__(256) void selector_kernel(
    const float* __restrict__ x, const float* __restrict__ Wsel,
    const float* __restrict__ bsel,
    __hip_bfloat16* __restrict__ x_bf, float* __restrict__ sw,
    float4* __restrict__ out4)
{
  // fused out-zeroing (independent of selector math; completes before FC2)
  {
    const int base = blockIdx.x * 1024 + threadIdx.x;
    const float4 z4 = {0.f, 0.f, 0.f, 0.f};
#pragma unroll
    for (int r = 0; r < 4; r++) out4[base + r * 256] = z4;
  }

  const int lane = threadIdx.x & 63;
  const int wave = threadIdx.x >> 6;
  const int n = blockIdx.x * 4 + wave;
  const float4* xr4 = (const float4*)(x + (size_t)n * DIN);
  ushort4* xb4 = (ushort4*)(x_bf + (size_t)n * DIN);

  float acc[8];
#pragma unroll
  for (int e = 0; e < 8; e++) acc[e] = 0.f;

#pragma unroll
  for (int i = 0; i < 4; i++) {
    const int d4 = lane + i * 64;          // float4 index; covers dims 4*d4..4*d4+3
    const float4 xv = xr4[d4];
    ushort4 p;
    p.x = bf16_bits(xv.x);
    p.y = bf16_bits(xv.y);
    p.z = bf16_bits(xv.z);
    p.w = bf16_bits(xv.w);
    xb4[d4] = p;
    const float xs[4] = {xv.x, xv.y, xv.z, xv.w};
#pragma unroll
    for (int q = 0; q < 4; q++) {
      const int d = d4 * 4 + q;
      const float4* wr = (const float4*)(Wsel + d * 8);
      const float4 wlo = wr[0], whi = wr[1];
      const float xv1 = xs[q];
      acc[0] += xv1 * wlo.x; acc[1] += xv1 * wlo.y;
      acc[2] += xv1 * wlo.z; acc[3] += xv1 * wlo.w;
      acc[4] += xv1 * whi.x; acc[5] += xv1 * whi.y;
      acc[6] += xv1 * whi.z; acc[7] += xv1 * whi.w;
    }
  }
#pragma unroll
  for (int off = 32; off >= 1; off >>= 1)
#pragma unroll
    for (int e = 0; e < 8; e++) acc[e] += __shfl_xor(acc[e], off);

  if (lane == 0) {
    float w[8];
    float mx = -1e30f;
#pragma unroll
    for (int e = 0; e < 8; e++) { w[e] = acc[e] + bsel[e]; mx = fmaxf(mx, w[e]); }
    float s = 0.f;
#pragma unroll
    for (int e = 0; e < 8; e++) { w[e] = expf(w[e] - mx); s += w[e]; }
    const float inv = 1.f / s;
#pragma unroll
    for (int e = 0; e < 8; e++) w[e] *= inv;

    // stable descending argsort (insertion sort; strict < keeps ties stable)
    float wsrt[8]; int ord[8];
    for (int k = 0; k < 8; k++) {
      const float v = w[k];
      int j = k;
      while (j > 0 && wsrt[j - 1] < v) { wsrt[j] = wsrt[j - 1]; ord[j] = ord[j - 1]; j--; }
      wsrt[j] = v; ord[j] = k;
    }
    // capped cumulative sparse weights (sorted order)
    float cum = 0.f, sws[8];
    for (int k = 0; k < 8; k++) {
      cum += wsrt[k];
      const float capped = fminf(cum, CAP);
      sws[k] = fmaxf(capped - cum + wsrt[k], 0.f);
    }
    // faithful to torch.gather(sparse_weight, 1, index): sw[j] = sws[ord[j]]
    for (int j = 0; j < 8; j++) sw[(size_t)n * 8 + j] = sws[ord[j]];
  }
}

// ---------------------------------------------------------------------------
// FUSED: per-expert token compaction (z==16, first 8 blocks; 256 thr = 4
// waves, 32 chunks of 256 tokens, ballot->scan, zero atomics) + weight
// transpose/convert (z<16, former convert_weights_kernel).
// ---------------------------------------------------------------------------
__global__ __launch_bounds__(256) void compact_convert_kernel(
    const float* __restrict__ sw, int* __restrict__ idx, int* __restrict__ cnt,
    const float* __restrict__ W1, const float* __restrict__ W2,
    __hip_bfloat16* __restrict__ W1t, __hip_bfloat16* __restrict__ W2t)
{
  const int z = blockIdx.z;
  if (z == 16) {
    const int bid = blockIdx.x + 32 * blockIdx.y;
    if (bid >= 8) return;
    const int e = bid;
    const int t = threadIdx.x;
    const int lane = t & 63;
    const int wv = t >> 6;
    __shared__ int wave_base[4];
    __shared__ int chunk_total;
    int base = 0;
    for (int c = 0; c < 32; c++) {
      const int tok = c * 256 + t;
      const bool act = sw[(size_t)tok * 8 + e] > 0.f;
      const unsigned long long m = __ballot(act);
      const int before = __popcll(m & ((1ull << lane) - 1ull));
      if (lane == 0) wave_base[wv] = __popcll(m);
      __syncthreads();
      if (t == 0) {
        int s = 0;
        for (int w = 0; w < 4; w++) { const int v = wave_base[w]; wave_base[w] = s; s += v; }
        chunk_total = s;
      }
      __syncthreads();
      if (act) idx[e * N_TOK + base + wave_base[wv] + before] = tok;
      base += chunk_total;
      __syncthreads();   // protect wave_base/chunk_total before next chunk
    }
    if (t == 0) cnt[e] = base;
    return;
  }

  // ---- convert: W1[e][k][n] -> W1t[e][n][k] bf16 ; W2 likewise ----
  __shared__ float tile[32][33];
  const float* src = (z & 8) ? W2 : W1;
  __hip_bfloat16* dst = (z & 8) ? W2t : W1t;
  const int e = z & 7;
  src += (size_t)e * 1024 * 1024;
  dst += (size_t)e * 1024 * 1024;
  const int R = blockIdx.y * 32, C = blockIdx.x * 32;
  const int c = threadIdx.x & 31, r0 = threadIdx.x >> 5;
#pragma unroll
  for (int p = 0; p < 4; p++) {
    const int r = r0 + p * 8;
    tile[r][c] = src[(size_t)(R + r) * 1024 + C + c];
  }
  __syncthreads();
#pragma unroll
  for (int p = 0; p < 4; p++) {
    const int r = r0 + p * 8;
    dst[(size_t)(C + r) * 1024 + R + c] = __float2bfloat16(tile[c][r]);
  }
}

// ---------------------------------------------------------------------------
// Compacted per-expert GEMM, 128x128 tile, BK=32, round-1 double-buffered
// structure (best measured), plus XCD-LOCALITY REMAP.
//
// Remap rationale: lid%8 selects the XCD (round-robin dispatch). We choose
// (e, mb, nb) from lid so that the 8 n-blocks consuming one A-tile (e,mb)
// share an XCD (A fetched once per XCD-L2), and the per-k-step B working set
// per XCD is ~512 KB (L2-resident). Balanced across XCDs regardless of
// cnt[e] skew because each XCD gets every 8th m-block of every expert.
//   xcd = lid&7 ; s = lid>>3 ; nb = s&7 ; g = s>>3 ;
//   e = g&7 ; mb = ((xcd - e)&7) + 8*(g>>3)      // (e+mb)%8 == xcd
// Bijective onto (e in 8, mb in 64, nb in 8).
//
// MODE 0 (FC1): A = gather(x_bf, idx[e]);  hpool[e] = bf16(relu(A W1t^T + b1))
// MODE 1 (FC2): A = hpool[e];  out[idx[e][m]] += sw * (A W2t^T + b2)  (atomic)
// ---------------------------------------------------------------------------
#define BUFO (128 * 32)   // elements per LDS buffer

template <int MODE>
__global__ __launch_bounds__(256, 2) void moe_gemm(
    const __hip_bfloat16* __restrict__ x_bf,
    __hip_bfloat16* __restrict__ hpool,
    const __hip_bfloat16* __restrict__ Wt,
    const float* __restrict__ biasAll,
    const float* __restrict__ sw,
    const int* __restrict__ idx, const int* __restrict__ cnt,
    float* __restrict__ out)
{
  // ---- XCD-locality remap ----
  const int lid = blockIdx.x + (blockIdx.y << 3) + (blockIdx.z << 9);
  const int xcd = lid & 7;
  const int s_ = lid >> 3;
  const int nb = s_ & 7;
  const int g  = s_ >> 3;          // 0..63
  const int e  = g & 7;
  const int mb = ((xcd - e) & 7) + ((g >> 3) << 3);

  const int count = cnt[e];
  const int m0 = mb * 128;
  if (m0 >= count) return;
  const int n0 = nb * 128;

  __shared__ __align__(16) __hip_bfloat16 sA[2 * BUFO];
  __shared__ __align__(16) __hip_bfloat16 sB[2 * BUFO];
  const int t = threadIdx.x;
  const int lane = t & 63;
  const int wave = t >> 6;
  const int wm = (wave & 1) * 64;
  const int wn = (wave >> 1) * 64;
  const int* idx_e = idx + e * N_TOK;
  const float* bias = biasAll + e * 1024;

  floatx4 acc[4][4];
#pragma unroll
  for (int i = 0; i < 4; i++)
#pragma unroll
    for (int j = 0; j < 4; j++) acc[i][j] = (floatx4){0.f, 0.f, 0.f, 0.f};

  // staging addresses: thread t loads 16B for rows sr and sr+64
  const int sr = t >> 2;
  const int sc = (t & 3) * 8;
  const __hip_bfloat16* Ag0;
  const __hip_bfloat16* Ag1;
  if (MODE == 0) {
    const int t0 = idx_e[min(m0 + sr, count - 1)];       // clamp tail (valid rows)
    const int t1 = idx_e[min(m0 + sr + 64, count - 1)];
    Ag0 = x_bf + (size_t)t0 * 1024 + sc;
    Ag1 = x_bf + (size_t)t1 * 1024 + sc;
  } else {
    const __hip_bfloat16* hp = hpool + (size_t)e * N_TOK * 1024;
    Ag0 = hp + (size_t)(m0 + sr) * 1024 + sc;            // tail reads scratch: finite
    Ag1 = hp + (size_t)(m0 + sr + 64) * 1024 + sc;
  }
  const __hip_bfloat16* Bg = Wt + (size_t)e * 1024 * 1024 + (size_t)(n0 + sr) * 1024 + sc;
  __hip_bfloat16* lA = &sA[sr * 32 + sc];
  __hip_bfloat16* lB = &sB[sr * 32 + sc];

  const int rf = lane & 15;
  const int k8 = (lane >> 4) * 8;
  const int roA = (wm + rf) * 32 + k8;
  const int roB = (wn + rf) * 32 + k8;

  // prologue: stage K-tile 0 into buffer 0
  async_load16(Ag0, lA);
  async_load16(Ag1, lA + 64 * 32);
  async_load16(Bg, lB);
  async_load16(Bg + (size_t)64 * 1024, lB + 64 * 32);
  __syncthreads();

  // STEP(kt, RB, WB): stage tile kt+1 into buffer WB, compute tile kt from RB.
#define STEP(KT, RB, WB)                                                        \
  {                                                                             \
    const int knext = ((KT) + 1) * 32;                                          \
    if (knext < 1024) {                                                         \
      async_load16(Ag0 + knext, lA + (WB) * BUFO);                              \
      async_load16(Ag1 + knext, lA + (WB) * BUFO + 64 * 32);                    \
      async_load16(Bg + knext, lB + (WB) * BUFO);                               \
      async_load16(Bg + (size_t)64 * 1024 + knext, lB + (WB) * BUFO + 64 * 32); \
    }                                                                           \
    const __hip_bfloat16* pA = &sA[(RB) * BUFO + roA];                          \
    const __hip_bfloat16* pB = &sB[(RB) * BUFO + roB];                          \
    short8 aF[4], bF[4];                                                        \
    _Pragma("unroll")                                                           \
    for (int i = 0; i < 4; i++) aF[i] = *(const short8*)(pA + i * 16 * 32);     \
    _Pragma("unroll")                                                           \
    for (int j = 0; j < 4; j++) bF[j] = *(const short8*)(pB + j * 16 * 32);     \
    _Pragma("unroll")                                                           \
    for (int i = 0; i < 4; i++)                                                 \
      _Pragma("unroll")                                                         \
      for (int j = 0; j < 4; j++)                                               \
        acc[i][j] = __builtin_amdgcn_mfma_f32_16x16x32_bf16(aF[i], bF[j],       \
                                                            acc[i][j], 0, 0, 0);\
    __syncthreads();                                                            \
  }

  for (int kt = 0; kt < 32; kt += 2) {
    STEP(kt, 0, 1);
    STEP(kt + 1, 1, 0);
  }
#undef STEP

  // epilogue: C/D layout col = lane&15, row = (lane>>4)*4 + reg
  const int quad = lane >> 4;
  const int cn = lane & 15;
#pragma unroll
  for (int i = 0; i < 4; i++) {
#pragma unroll
    for (int r = 0; r < 4; r++) {
      const int gm = m0 + wm + i * 16 + quad * 4 + r;
      if (gm >= count) continue;
      int tok = 0; float swv = 0.f;
      if (MODE == 1) {
        tok = idx_e[gm];
        swv = sw[tok * 8 + e];
      }
#pragma unroll
      for (int j = 0; j < 4; j++) {
        const int gn = n0 + wn + j * 16 + cn;
        const float v = acc[i][j][r] + bias[gn];
        if (MODE == 0) {
          hpool[((size_t)e * N_TOK + gm) * 1024 + gn] = __float2bfloat16(fmaxf(v, 0.f));
        } else {
          unsafeAtomicAdd(&out[(size_t)tok * 1024 + gn], swv * v);
        }
      }
    }
  }
}

// ---------------------------------------------------------------------------
extern "C" void kernel_launch(void* const* d_in, const int* in_sizes, int n_in,
                              void* d_out, int out_size, void* d_ws, size_t ws_size,
                              hipStream_t stream) {
  const float* x    = (const float*)d_in[0];
  const float* Wsel = (const float*)d_in[1];
  const float* bsel = (const float*)d_in[2];
  const float* W1   = (const float*)d_in[3];
  const float* b1   = (const float*)d_in[4];
  const float* W2   = (const float*)d_in[5];
  const float* b2   = (const float*)d_in[6];
  float* out = (float*)d_out;

  char* ws = (char*)d_ws;
  __hip_bfloat16* x_bf = (__hip_bfloat16*)ws; ws += (size_t)N_TOK * DIN * 2;
  __hip_bfloat16* W1t  = (__hip_bfloat16*)ws; ws += (size_t)NE * DIN * HID * 2;
  __hip_bfloat16* W2t  = (__hip_bfloat16*)ws; ws += (size_t)NE * HID * DOUT * 2;
  float* sw            = (float*)ws;          ws += (size_t)N_TOK * NE * 4;
  int* idx             = (int*)ws;            ws += (size_t)NE * N_TOK * 4;
  int* cnt             = (int*)ws;            ws += 256;
  __hip_bfloat16* hpool = (__hip_bfloat16*)ws;  // NE*N_TOK*HID*2 = 134 MB

  selector_kernel<<<N_TOK / 4, 256, 0, stream>>>(x, Wsel, bsel, x_bf, sw,
                                                 (float4*)out);
  compact_convert_kernel<<<dim3(32, 32, 17), 256, 0, stream>>>(
      sw, idx, cnt, W1, W2, W1t, W2t);

  moe_gemm<0><<<dim3(HID / 128, N_TOK / 128, NE), 256, 0, stream>>>(
      x_bf, hpool, W1t, b1, sw, idx, cnt, out);
  moe_gemm<1><<<dim3(DOUT / 128, N_TOK / 128, NE), 256, 0, stream>>>(
      x_bf, hpool, W2t, b2, sw, idx, cnt, out);
}

// Round 4
// 315.090 us; speedup vs baseline: 1.0951x; 1.0218x over previous
//
#include <hip/hip_runtime.h>
#include <hip/hip_bf16.h>
#include <stdint.h>

#define N_TOK 8192
#define DIN   1024
#define DOUT  1024
#define HID   1024
#define NE    8
#define CAP   0.8f   // 1 - EPS

typedef __attribute__((ext_vector_type(8))) short short8;
typedef __attribute__((ext_vector_type(4))) float floatx4;

__device__ __forceinline__ void async_load16(const void* g, void* l) {
  __builtin_amdgcn_global_load_lds(
      (const __attribute__((address_space(1))) void*)g,
      (__attribute__((address_space(3))) void*)l,
      16, 0, 0);
}

__device__ __forceinline__ unsigned short bf16_bits(float f) {
  return __builtin_bit_cast(unsigned short, __float2bfloat16(f));
}

// ---------------------------------------------------------------------------
// Selector: logits = x @ Wsel + bsel ; softmax ; capped-cumsum sparse weights.
// Emits x as bf16 + sw. ALSO zero-fills d_out (fused former zero_kernel).
// ---------------------------------------------------------------------------
__global__ __launch_bounds__(256) void selector_kernel(
    const float* __restrict__ x, const float* __restrict__ Wsel,
    const float* __restrict__ bsel,
    __hip_bfloat16* __restrict__ x_bf, float* __restrict__ sw,
    float4* __restrict__ out4)
{
  // fused out-zeroing (independent of selector math; completes before FC2)
  {
    const int base = blockIdx.x * 1024 + threadIdx.x;
    const float4 z4 = {0.f, 0.f, 0.f, 0.f};
#pragma unroll
    for (int r = 0; r < 4; r++) out4[base + r * 256] = z4;
  }

  const int lane = threadIdx.x & 63;
  const int wave = threadIdx.x >> 6;
  const int n = blockIdx.x * 4 + wave;
  const float4* xr4 = (const float4*)(x + (size_t)n * DIN);
  ushort4* xb4 = (ushort4*)(x_bf + (size_t)n * DIN);

  float acc[8];
#pragma unroll
  for (int e = 0; e < 8; e++) acc[e] = 0.f;

#pragma unroll
  for (int i = 0; i < 4; i++) {
    const int d4 = lane + i * 64;          // float4 index; covers dims 4*d4..4*d4+3
    const float4 xv = xr4[d4];
    ushort4 p;
    p.x = bf16_bits(xv.x);
    p.y = bf16_bits(xv.y);
    p.z = bf16_bits(xv.z);
    p.w = bf16_bits(xv.w);
    xb4[d4] = p;
    const float xs[4] = {xv.x, xv.y, xv.z, xv.w};
#pragma unroll
    for (int q = 0; q < 4; q++) {
      const int d = d4 * 4 + q;
      const float4* wr = (const float4*)(Wsel + d * 8);
      const float4 wlo = wr[0], whi = wr[1];
      const float xv1 = xs[q];
      acc[0] += xv1 * wlo.x; acc[1] += xv1 * wlo.y;
      acc[2] += xv1 * wlo.z; acc[3] += xv1 * wlo.w;
      acc[4] += xv1 * whi.x; acc[5] += xv1 * whi.y;
      acc[6] += xv1 * whi.z; acc[7] += xv1 * whi.w;
    }
  }
#pragma unroll
  for (int off = 32; off >= 1; off >>= 1)
#pragma unroll
    for (int e = 0; e < 8; e++) acc[e] += __shfl_xor(acc[e], off);

  if (lane == 0) {
    float w[8];
    float mx = -1e30f;
#pragma unroll
    for (int e = 0; e < 8; e++) { w[e] = acc[e] + bsel[e]; mx = fmaxf(mx, w[e]); }
    float s = 0.f;
#pragma unroll
    for (int e = 0; e < 8; e++) { w[e] = expf(w[e] - mx); s += w[e]; }
    const float inv = 1.f / s;
#pragma unroll
    for (int e = 0; e < 8; e++) w[e] *= inv;

    // stable descending argsort (insertion sort; strict < keeps ties stable)
    float wsrt[8]; int ord[8];
    for (int k = 0; k < 8; k++) {
      const float v = w[k];
      int j = k;
      while (j > 0 && wsrt[j - 1] < v) { wsrt[j] = wsrt[j - 1]; ord[j] = ord[j - 1]; j--; }
      wsrt[j] = v; ord[j] = k;
    }
    // capped cumulative sparse weights (sorted order)
    float cum = 0.f, sws[8];
    for (int k = 0; k < 8; k++) {
      cum += wsrt[k];
      const float capped = fminf(cum, CAP);
      sws[k] = fmaxf(capped - cum + wsrt[k], 0.f);
    }
    // faithful to torch.gather(sparse_weight, 1, index): sw[j] = sws[ord[j]]
    for (int j = 0; j < 8; j++) sw[(size_t)n * 8 + j] = sws[ord[j]];
  }
}

// ---------------------------------------------------------------------------
// FUSED 1024-thread kernel: weight transpose/convert + per-expert compaction.
// grid (16,16,17):
//   z < 16 : convert 64x64 tile. float4 coalesced loads; transposed stores are
//            full 128-B lines (16 threads x ushort4 per dst row). Padded LDS.
//   z == 16: compact (blocks 0..7 only): 16 waves, 8 chunks of 1024 tokens,
//            ballot -> LDS scan -> ordered compaction. Zero global atomics.
// ---------------------------------------------------------------------------
__global__ __launch_bounds__(1024) void compact_convert_kernel(
    const float* __restrict__ sw, int* __restrict__ idx, int* __restrict__ cnt,
    const float* __restrict__ W1, const float* __restrict__ W2,
    __hip_bfloat16* __restrict__ W1t, __hip_bfloat16* __restrict__ W2t)
{
  const int z = blockIdx.z;
  const int t = threadIdx.x;

  if (z == 16) {
    const int bid = blockIdx.x + 16 * blockIdx.y;
    if (bid >= 8) return;
    const int e = bid;
    const int lane = t & 63;
    const int wv = t >> 6;
    __shared__ int wave_base[16];
    __shared__ int chunk_total;
    int base = 0;
#pragma unroll
    for (int c = 0; c < 8; c++) {
      const int tok = c * 1024 + t;
      const bool act = sw[(size_t)tok * 8 + e] > 0.f;
      const unsigned long long m = __ballot(act);
      const int before = __popcll(m & ((1ull << lane) - 1ull));
      if (lane == 0) wave_base[wv] = __popcll(m);
      __syncthreads();
      if (t == 0) {
        int s = 0;
        for (int w = 0; w < 16; w++) { const int v = wave_base[w]; wave_base[w] = s; s += v; }
        chunk_total = s;
      }
      __syncthreads();
      if (act) idx[e * N_TOK + base + wave_base[wv] + before] = tok;
      base += chunk_total;
      __syncthreads();   // protect wave_base/chunk_total before next chunk
    }
    if (t == 0) cnt[e] = base;
    return;
  }

  // ---- convert: W[e][r][c] fp32 -> Wt[e][c][r] bf16, 64x64 tile ----
  __shared__ unsigned short tile[64][65];
  const float* src = (z & 8) ? W2 : W1;
  __hip_bfloat16* dst = (z & 8) ? W2t : W1t;
  const int e = z & 7;
  src += (size_t)e * 1024 * 1024;
  unsigned short* dstu = (unsigned short*)dst + (size_t)e * 1024 * 1024;
  const int R = blockIdx.y * 64, C = blockIdx.x * 64;

  // load: thread (row = t>>4, col4 = t&15) reads float4 -> bf16 -> LDS
  {
    const int row = t >> 4;
    const int col4 = t & 15;
    const float4 v = *(const float4*)(src + (size_t)(R + row) * 1024 + C + col4 * 4);
    tile[row][col4 * 4 + 0] = bf16_bits(v.x);
    tile[row][col4 * 4 + 1] = bf16_bits(v.y);
    tile[row][col4 * 4 + 2] = bf16_bits(v.z);
    tile[row][col4 * 4 + 3] = bf16_bits(v.w);
  }
  __syncthreads();
  // store: thread (d = t>>4, j = t&15) writes dst[C+d][R + 4j .. 4j+3]
  {
    const int d = t >> 4;
    const int j = t & 15;
    ushort4 o;
    o.x = tile[j * 4 + 0][d];
    o.y = tile[j * 4 + 1][d];
    o.z = tile[j * 4 + 2][d];
    o.w = tile[j * 4 + 3][d];
    *(ushort4*)(dstu + (size_t)(C + d) * 1024 + R + j * 4) = o;
  }
}

// ---------------------------------------------------------------------------
// Compacted per-expert GEMM, 128x128 tile, BK=32, double-buffered LDS
// (round-1 structure — best measured at 84.0 us; XCD remap reverted: it cut
// FETCH 115->79 MB but cost +6% time, locality not binding).
// MODE 0 (FC1): A = gather(x_bf, idx[e]);  hpool[e] = bf16(relu(A W1t^T + b1))
// MODE 1 (FC2): A = hpool[e];  out[idx[e][m]] += sw * (A W2t^T + b2)  (atomic)
// ---------------------------------------------------------------------------
#define BUFO (128 * 32)   // elements per LDS buffer

template <int MODE>
__global__ __launch_bounds__(256, 2) void moe_gemm(
    const __hip_bfloat16* __restrict__ x_bf,
    __hip_bfloat16* __restrict__ hpool,
    const __hip_bfloat16* __restrict__ Wt,
    const float* __restrict__ biasAll,
    const float* __restrict__ sw,
    const int* __restrict__ idx, const int* __restrict__ cnt,
    float* __restrict__ out)
{
  const int e = blockIdx.z;
  const int count = cnt[e];
  const int m0 = blockIdx.y * 128;
  if (m0 >= count) return;
  const int n0 = blockIdx.x * 128;

  __shared__ __align__(16) __hip_bfloat16 sA[2 * BUFO];
  __shared__ __align__(16) __hip_bfloat16 sB[2 * BUFO];
  const int t = threadIdx.x;
  const int lane = t & 63;
  const int wave = t >> 6;
  const int wm = (wave & 1) * 64;
  const int wn = (wave >> 1) * 64;
  const int* idx_e = idx + e * N_TOK;
  const float* bias = biasAll + e * 1024;

  floatx4 acc[4][4];
#pragma unroll
  for (int i = 0; i < 4; i++)
#pragma unroll
    for (int j = 0; j < 4; j++) acc[i][j] = (floatx4){0.f, 0.f, 0.f, 0.f};

  // staging addresses: thread t loads 16B for rows sr and sr+64
  const int sr = t >> 2;
  const int sc = (t & 3) * 8;
  const __hip_bfloat16* Ag0;
  const __hip_bfloat16* Ag1;
  if (MODE == 0) {
    const int t0 = idx_e[min(m0 + sr, count - 1)];       // clamp tail (valid rows)
    const int t1 = idx_e[min(m0 + sr + 64, count - 1)];
    Ag0 = x_bf + (size_t)t0 * 1024 + sc;
    Ag1 = x_bf + (size_t)t1 * 1024 + sc;
  } else {
    const __hip_bfloat16* hp = hpool + (size_t)e * N_TOK * 1024;
    Ag0 = hp + (size_t)(m0 + sr) * 1024 + sc;            // tail reads scratch: finite
    Ag1 = hp + (size_t)(m0 + sr + 64) * 1024 + sc;
  }
  const __hip_bfloat16* Bg = Wt + (size_t)e * 1024 * 1024 + (size_t)(n0 + sr) * 1024 + sc;
  __hip_bfloat16* lA = &sA[sr * 32 + sc];
  __hip_bfloat16* lB = &sB[sr * 32 + sc];

  const int rf = lane & 15;
  const int k8 = (lane >> 4) * 8;
  const int roA = (wm + rf) * 32 + k8;
  const int roB = (wn + rf) * 32 + k8;

  // prologue: stage K-tile 0 into buffer 0
  async_load16(Ag0, lA);
  async_load16(Ag1, lA + 64 * 32);
  async_load16(Bg, lB);
  async_load16(Bg + (size_t)64 * 1024, lB + 64 * 32);
  __syncthreads();

  // STEP(kt, RB, WB): stage tile kt+1 into buffer WB, compute tile kt from RB.
#define STEP(KT, RB, WB)                                                        \
  {                                                                             \
    const int knext = ((KT) + 1) * 32;                                          \
    if (knext < 1024) {                                                         \
      async_load16(Ag0 + knext, lA + (WB) * BUFO);                              \
      async_load16(Ag1 + knext, lA + (WB) * BUFO + 64 * 32);                    \
      async_load16(Bg + knext, lB + (WB) * BUFO);                               \
      async_load16(Bg + (size_t)64 * 1024 + knext, lB + (WB) * BUFO + 64 * 32); \
    }                                                                           \
    const __hip_bfloat16* pA = &sA[(RB) * BUFO + roA];                          \
    const __hip_bfloat16* pB = &sB[(RB) * BUFO + roB];                          \
    short8 aF[4], bF[4];                                                        \
    _Pragma("unroll")                                                           \
    for (int i = 0; i < 4; i++) aF[i] = *(const short8*)(pA + i * 16 * 32);     \
    _Pragma("unroll")                                                           \
    for (int j = 0; j < 4; j++) bF[j] = *(const short8*)(pB + j * 16 * 32);     \
    _Pragma("unroll")                                                           \
    for (int i = 0; i < 4; i++)                                                 \
      _Pragma("unroll")                                                         \
      for (int j = 0; j < 4; j++)                                               \
        acc[i][j] = __builtin_amdgcn_mfma_f32_16x16x32_bf16(aF[i], bF[j],       \
                                                            acc[i][j], 0, 0, 0);\
    __syncthreads();                                                            \
  }

  for (int kt = 0; kt < 32; kt += 2) {
    STEP(kt, 0, 1);
    STEP(kt + 1, 1, 0);
  }
#undef STEP

  // epilogue: C/D layout col = lane&15, row = (lane>>4)*4 + reg
  const int quad = lane >> 4;
  const int cn = lane & 15;
#pragma unroll
  for (int i = 0; i < 4; i++) {
#pragma unroll
    for (int r = 0; r < 4; r++) {
      const int gm = m0 + wm + i * 16 + quad * 4 + r;
      if (gm >= count) continue;
      int tok = 0; float swv = 0.f;
      if (MODE == 1) {
        tok = idx_e[gm];
        swv = sw[tok * 8 + e];
      }
#pragma unroll
      for (int j = 0; j < 4; j++) {
        const int gn = n0 + wn + j * 16 + cn;
        const float v = acc[i][j][r] + bias[gn];
        if (MODE == 0) {
          hpool[((size_t)e * N_TOK + gm) * 1024 + gn] = __float2bfloat16(fmaxf(v, 0.f));
        } else {
          unsafeAtomicAdd(&out[(size_t)tok * 1024 + gn], swv * v);
        }
      }
    }
  }
}

// ---------------------------------------------------------------------------
extern "C" void kernel_launch(void* const* d_in, const int* in_sizes, int n_in,
                              void* d_out, int out_size, void* d_ws, size_t ws_size,
                              hipStream_t stream) {
  const float* x    = (const float*)d_in[0];
  const float* Wsel = (const float*)d_in[1];
  const float* bsel = (const float*)d_in[2];
  const float* W1   = (const float*)d_in[3];
  const float* b1   = (const float*)d_in[4];
  const float* W2   = (const float*)d_in[5];
  const float* b2   = (const float*)d_in[6];
  float* out = (float*)d_out;

  char* ws = (char*)d_ws;
  __hip_bfloat16* x_bf = (__hip_bfloat16*)ws; ws += (size_t)N_TOK * DIN * 2;
  __hip_bfloat16* W1t  = (__hip_bfloat16*)ws; ws += (size_t)NE * DIN * HID * 2;
  __hip_bfloat16* W2t  = (__hip_bfloat16*)ws; ws += (size_t)NE * HID * DOUT * 2;
  float* sw            = (float*)ws;          ws += (size_t)N_TOK * NE * 4;
  int* idx             = (int*)ws;            ws += (size_t)NE * N_TOK * 4;
  int* cnt             = (int*)ws;            ws += 256;
  __hip_bfloat16* hpool = (__hip_bfloat16*)ws;  // NE*N_TOK*HID*2 = 134 MB

  selector_kernel<<<N_TOK / 4, 256, 0, stream>>>(x, Wsel, bsel, x_bf, sw,
                                                 (float4*)out);
  compact_convert_kernel<<<dim3(16, 16, 17), 1024, 0, stream>>>(
      sw, idx, cnt, W1, W2, W1t, W2t);

  moe_gemm<0><<<dim3(HID / 128, N_TOK / 128, NE), 256, 0, stream>>>(
      x_bf, hpool, W1t, b1, sw, idx, cnt, out);
  moe_gemm<1><<<dim3(DOUT / 128, N_TOK / 128, NE), 256, 0, stream>>>(
      x_bf, hpool, W2t, b2, sw, idx, cnt, out);
}

// Round 5
// 296.029 us; speedup vs baseline: 1.1656x; 1.0644x over previous
//
#include <hip/hip_runtime.h>
#include <hip/hip_bf16.h>
#include <stdint.h>

#define N_TOK 8192
#define DIN   1024
#define DOUT  1024
#define HID   1024
#define NE    8
#define CAP   0.8f   // 1 - EPS

typedef __attribute__((ext_vector_type(8))) short short8;
typedef __attribute__((ext_vector_type(4))) float floatx4;

__device__ __forceinline__ void async_load16(const void* g, void* l) {
  __builtin_amdgcn_global_load_lds(
      (const __attribute__((address_space(1))) void*)g,
      (__attribute__((address_space(3))) void*)l,
      16, 0, 0);
}

__device__ __forceinline__ unsigned short bf16_bits(float f) {
  return __builtin_bit_cast(unsigned short, __float2bfloat16(f));
}

// ---------------------------------------------------------------------------
// Selector, COALESCED-Wsel version. 512 blocks x 256 thr; each wave owns 4
// tokens. Round-4 analysis: old layout read Wsel with 128-B lane stride ->
// 64 cache lines per load instruction, ~131k L1 line-requests per CU. New:
// d = lane + i*64 so Wsel row reads are lane-contiguous (32-B stride), and
// acc[4][8] amortizes each Wsel read over 4 tokens (16x fewer line-requests).
// Also zero-fills d_out (16 float4 per thread) and emits x_bf + sw.
// ---------------------------------------------------------------------------
__global__ __launch_bounds__(256) void selector_kernel(
    const float* __restrict__ x, const float* __restrict__ Wsel,
    const float* __restrict__ bsel,
    __hip_bfloat16* __restrict__ x_bf, float* __restrict__ sw,
    float4* __restrict__ out4)
{
  // fused out-zeroing: 512 blocks * 256 thr * 16 float4 = 8192*1024 floats
  {
    const int base = blockIdx.x * 4096 + threadIdx.x;
    const float4 z4 = {0.f, 0.f, 0.f, 0.f};
#pragma unroll
    for (int r = 0; r < 16; r++) out4[base + r * 256] = z4;
  }

  const int lane = threadIdx.x & 63;
  const int wave = threadIdx.x >> 6;
  const int tok0 = blockIdx.x * 16 + wave * 4;
  const float* xr = x + (size_t)tok0 * DIN;
  const float4* W4 = (const float4*)Wsel;

  float acc[4][8];
#pragma unroll
  for (int m = 0; m < 4; m++)
#pragma unroll
    for (int e = 0; e < 8; e++) acc[m][e] = 0.f;

#pragma unroll
  for (int i = 0; i < 16; i++) {
    const int d = lane + i * 64;
    const float4 wlo = W4[d * 2];      // lanes: 32-B stride -> coalesced
    const float4 whi = W4[d * 2 + 1];
#pragma unroll
    for (int m = 0; m < 4; m++) {
      const float xv = xr[m * DIN + d];  // lanes: 4-B stride -> coalesced
      acc[m][0] += xv * wlo.x; acc[m][1] += xv * wlo.y;
      acc[m][2] += xv * wlo.z; acc[m][3] += xv * wlo.w;
      acc[m][4] += xv * whi.x; acc[m][5] += xv * whi.y;
      acc[m][6] += xv * whi.z; acc[m][7] += xv * whi.w;
    }
  }
  // full-wave butterfly: afterwards every lane holds all 32 sums
#pragma unroll
  for (int off = 32; off >= 1; off >>= 1)
#pragma unroll
    for (int m = 0; m < 4; m++)
#pragma unroll
      for (int e = 0; e < 8; e++) acc[m][e] += __shfl_xor(acc[m][e], off);

  if (lane < 4) {
    const int n = tok0 + lane;
    float w[8];
    float mx = -1e30f;
#pragma unroll
    for (int e = 0; e < 8; e++) { w[e] = acc[lane][e] + bsel[e]; mx = fmaxf(mx, w[e]); }
    float s = 0.f;
#pragma unroll
    for (int e = 0; e < 8; e++) { w[e] = expf(w[e] - mx); s += w[e]; }
    const float inv = 1.f / s;
#pragma unroll
    for (int e = 0; e < 8; e++) w[e] *= inv;

    // stable descending argsort (insertion sort; strict < keeps ties stable)
    float wsrt[8]; int ord[8];
    for (int k = 0; k < 8; k++) {
      const float v = w[k];
      int j = k;
      while (j > 0 && wsrt[j - 1] < v) { wsrt[j] = wsrt[j - 1]; ord[j] = ord[j - 1]; j--; }
      wsrt[j] = v; ord[j] = k;
    }
    // capped cumulative sparse weights (sorted order)
    float cum = 0.f, sws[8];
    for (int k = 0; k < 8; k++) {
      cum += wsrt[k];
      const float capped = fminf(cum, CAP);
      sws[k] = fmaxf(capped - cum + wsrt[k], 0.f);
    }
    // faithful to torch.gather(sparse_weight, 1, index): sw[j] = sws[ord[j]]
    for (int j = 0; j < 8; j++) sw[(size_t)n * 8 + j] = sws[ord[j]];
  }

  // bf16 conversion of the wave's 4 rows (float4 loads are cache-warm)
  const float4* xr4 = (const float4*)xr;
  ushort4* xb4 = (ushort4*)(x_bf + (size_t)tok0 * DIN);
#pragma unroll
  for (int m = 0; m < 4; m++)
#pragma unroll
    for (int i = 0; i < 4; i++) {
      const int d4 = lane + i * 64;
      const float4 xv = xr4[m * 256 + d4];
      ushort4 p;
      p.x = bf16_bits(xv.x);
      p.y = bf16_bits(xv.y);
      p.z = bf16_bits(xv.z);
      p.w = bf16_bits(xv.w);
      xb4[m * 256 + d4] = p;
    }
}

// ---------------------------------------------------------------------------
// FUSED 1024-thread kernel: weight transpose/convert + per-expert compaction.
// grid (16,16,17):
//   z < 16 : convert 64x64 tile. float4 coalesced loads; transposed stores are
//            full 128-B lines (16 threads x ushort4 per dst row). Padded LDS.
//   z == 16: compact (blocks 0..7 only): 16 waves, 8 chunks of 1024 tokens,
//            ballot -> LDS scan -> ordered compaction. Zero global atomics.
// ---------------------------------------------------------------------------
__global__ __launch_bounds__(1024) void compact_convert_kernel(
    const float* __restrict__ sw, int* __restrict__ idx, int* __restrict__ cnt,
    const float* __restrict__ W1, const float* __restrict__ W2,
    __hip_bfloat16* __restrict__ W1t, __hip_bfloat16* __restrict__ W2t)
{
  const int z = blockIdx.z;
  const int t = threadIdx.x;

  if (z == 16) {
    const int bid = blockIdx.x + 16 * blockIdx.y;
    if (bid >= 8) return;
    const int e = bid;
    const int lane = t & 63;
    const int wv = t >> 6;
    __shared__ int wave_base[16];
    __shared__ int chunk_total;
    int base = 0;
#pragma unroll
    for (int c = 0; c < 8; c++) {
      const int tok = c * 1024 + t;
      const bool act = sw[(size_t)tok * 8 + e] > 0.f;
      const unsigned long long m = __ballot(act);
      const int before = __popcll(m & ((1ull << lane) - 1ull));
      if (lane == 0) wave_base[wv] = __popcll(m);
      __syncthreads();
      if (t == 0) {
        int s = 0;
        for (int w = 0; w < 16; w++) { const int v = wave_base[w]; wave_base[w] = s; s += v; }
        chunk_total = s;
      }
      __syncthreads();
      if (act) idx[e * N_TOK + base + wave_base[wv] + before] = tok;
      base += chunk_total;
      __syncthreads();   // protect wave_base/chunk_total before next chunk
    }
    if (t == 0) cnt[e] = base;
    return;
  }

  // ---- convert: W[e][r][c] fp32 -> Wt[e][c][r] bf16, 64x64 tile ----
  __shared__ unsigned short tile[64][65];
  const float* src = (z & 8) ? W2 : W1;
  __hip_bfloat16* dst = (z & 8) ? W2t : W1t;
  const int e = z & 7;
  src += (size_t)e * 1024 * 1024;
  unsigned short* dstu = (unsigned short*)dst + (size_t)e * 1024 * 1024;
  const int R = blockIdx.y * 64, C = blockIdx.x * 64;

  // load: thread (row = t>>4, col4 = t&15) reads float4 -> bf16 -> LDS
  {
    const int row = t >> 4;
    const int col4 = t & 15;
    const float4 v = *(const float4*)(src + (size_t)(R + row) * 1024 + C + col4 * 4);
    tile[row][col4 * 4 + 0] = bf16_bits(v.x);
    tile[row][col4 * 4 + 1] = bf16_bits(v.y);
    tile[row][col4 * 4 + 2] = bf16_bits(v.z);
    tile[row][col4 * 4 + 3] = bf16_bits(v.w);
  }
  __syncthreads();
  // store: thread (d = t>>4, j = t&15) writes dst[C+d][R + 4j .. 4j+3]
  {
    const int d = t >> 4;
    const int j = t & 15;
    ushort4 o;
    o.x = tile[j * 4 + 0][d];
    o.y = tile[j * 4 + 1][d];
    o.z = tile[j * 4 + 2][d];
    o.w = tile[j * 4 + 3][d];
    *(ushort4*)(dstu + (size_t)(C + d) * 1024 + R + j * 4) = o;
  }
}

// ---------------------------------------------------------------------------
// Compacted per-expert GEMM, 128x128 tile, BK=32, double-buffered LDS
// (round-1 structure — best measured at 83.7-84.0 us).
// MODE 0 (FC1): A = gather(x_bf, idx[e]);  hpool[e] = bf16(relu(A W1t^T + b1))
// MODE 1 (FC2): A = hpool[e];  out[idx[e][m]] += sw * (A W2t^T + b2)  (atomic)
// ---------------------------------------------------------------------------
#define BUFO (128 * 32)   // elements per LDS buffer

template <int MODE>
__global__ __launch_bounds__(256, 2) void moe_gemm(
    const __hip_bfloat16* __restrict__ x_bf,
    __hip_bfloat16* __restrict__ hpool,
    const __hip_bfloat16* __restrict__ Wt,
    const float* __restrict__ biasAll,
    const float* __restrict__ sw,
    const int* __restrict__ idx, const int* __restrict__ cnt,
    float* __restrict__ out)
{
  const int e = blockIdx.z;
  const int count = cnt[e];
  const int m0 = blockIdx.y * 128;
  if (m0 >= count) return;
  const int n0 = blockIdx.x * 128;

  __shared__ __align__(16) __hip_bfloat16 sA[2 * BUFO];
  __shared__ __align__(16) __hip_bfloat16 sB[2 * BUFO];
  const int t = threadIdx.x;
  const int lane = t & 63;
  const int wave = t >> 6;
  const int wm = (wave & 1) * 64;
  const int wn = (wave >> 1) * 64;
  const int* idx_e = idx + e * N_TOK;
  const float* bias = biasAll + e * 1024;

  floatx4 acc[4][4];
#pragma unroll
  for (int i = 0; i < 4; i++)
#pragma unroll
    for (int j = 0; j < 4; j++) acc[i][j] = (floatx4){0.f, 0.f, 0.f, 0.f};

  // staging addresses: thread t loads 16B for rows sr and sr+64
  const int sr = t >> 2;
  const int sc = (t & 3) * 8;
  const __hip_bfloat16* Ag0;
  const __hip_bfloat16* Ag1;
  if (MODE == 0) {
    const int t0 = idx_e[min(m0 + sr, count - 1)];       // clamp tail (valid rows)
    const int t1 = idx_e[min(m0 + sr + 64, count - 1)];
    Ag0 = x_bf + (size_t)t0 * 1024 + sc;
    Ag1 = x_bf + (size_t)t1 * 1024 + sc;
  } else {
    const __hip_bfloat16* hp = hpool + (size_t)e * N_TOK * 1024;
    Ag0 = hp + (size_t)(m0 + sr) * 1024 + sc;            // tail reads scratch: finite
    Ag1 = hp + (size_t)(m0 + sr + 64) * 1024 + sc;
  }
  const __hip_bfloat16* Bg = Wt + (size_t)e * 1024 * 1024 + (size_t)(n0 + sr) * 1024 + sc;
  __hip_bfloat16* lA = &sA[sr * 32 + sc];
  __hip_bfloat16* lB = &sB[sr * 32 + sc];

  const int rf = lane & 15;
  const int k8 = (lane >> 4) * 8;
  const int roA = (wm + rf) * 32 + k8;
  const int roB = (wn + rf) * 32 + k8;

  // prologue: stage K-tile 0 into buffer 0
  async_load16(Ag0, lA);
  async_load16(Ag1, lA + 64 * 32);
  async_load16(Bg, lB);
  async_load16(Bg + (size_t)64 * 1024, lB + 64 * 32);
  __syncthreads();

  // STEP(kt, RB, WB): stage tile kt+1 into buffer WB, compute tile kt from RB.
#define STEP(KT, RB, WB)                                                        \
  {                                                                             \
    const int knext = ((KT) + 1) * 32;                                          \
    if (knext < 1024) {                                                         \
      async_load16(Ag0 + knext, lA + (WB) * BUFO);                              \
      async_load16(Ag1 + knext, lA + (WB) * BUFO + 64 * 32);                    \
      async_load16(Bg + knext, lB + (WB) * BUFO);                               \
      async_load16(Bg + (size_t)64 * 1024 + knext, lB + (WB) * BUFO + 64 * 32); \
    }                                                                           \
    const __hip_bfloat16* pA = &sA[(RB) * BUFO + roA];                          \
    const __hip_bfloat16* pB = &sB[(RB) * BUFO + roB];                          \
    short8 aF[4], bF[4];                                                        \
    _Pragma("unroll")                                                           \
    for (int i = 0; i < 4; i++) aF[i] = *(const short8*)(pA + i * 16 * 32);     \
    _Pragma("unroll")                                                           \
    for (int j = 0; j < 4; j++) bF[j] = *(const short8*)(pB + j * 16 * 32);     \
    _Pragma("unroll")                                                           \
    for (int i = 0; i < 4; i++)                                                 \
      _Pragma("unroll")                                                         \
      for (int j = 0; j < 4; j++)                                               \
        acc[i][j] = __builtin_amdgcn_mfma_f32_16x16x32_bf16(aF[i], bF[j],       \
                                                            acc[i][j], 0, 0, 0);\
    __syncthreads();                                                            \
  }

  for (int kt = 0; kt < 32; kt += 2) {
    STEP(kt, 0, 1);
    STEP(kt + 1, 1, 0);
  }
#undef STEP

  // epilogue: C/D layout col = lane&15, row = (lane>>4)*4 + reg
  const int quad = lane >> 4;
  const int cn = lane & 15;
#pragma unroll
  for (int i = 0; i < 4; i++) {
#pragma unroll
    for (int r = 0; r < 4; r++) {
      const int gm = m0 + wm + i * 16 + quad * 4 + r;
      if (gm >= count) continue;
      int tok = 0; float swv = 0.f;
      if (MODE == 1) {
        tok = idx_e[gm];
        swv = sw[tok * 8 + e];
      }
#pragma unroll
      for (int j = 0; j < 4; j++) {
        const int gn = n0 + wn + j * 16 + cn;
        const float v = acc[i][j][r] + bias[gn];
        if (MODE == 0) {
          hpool[((size_t)e * N_TOK + gm) * 1024 + gn] = __float2bfloat16(fmaxf(v, 0.f));
        } else {
          unsafeAtomicAdd(&out[(size_t)tok * 1024 + gn], swv * v);
        }
      }
    }
  }
}

// ---------------------------------------------------------------------------
extern "C" void kernel_launch(void* const* d_in, const int* in_sizes, int n_in,
                              void* d_out, int out_size, void* d_ws, size_t ws_size,
                              hipStream_t stream) {
  const float* x    = (const float*)d_in[0];
  const float* Wsel = (const float*)d_in[1];
  const float* bsel = (const float*)d_in[2];
  const float* W1   = (const float*)d_in[3];
  const float* b1   = (const float*)d_in[4];
  const float* W2   = (const float*)d_in[5];
  const float* b2   = (const float*)d_in[6];
  float* out = (float*)d_out;

  char* ws = (char*)d_ws;
  __hip_bfloat16* x_bf = (__hip_bfloat16*)ws; ws += (size_t)N_TOK * DIN * 2;
  __hip_bfloat16* W1t  = (__hip_bfloat16*)ws; ws += (size_t)NE * DIN * HID * 2;
  __hip_bfloat16* W2t  = (__hip_bfloat16*)ws; ws += (size_t)NE * HID * DOUT * 2;
  float* sw            = (float*)ws;          ws += (size_t)N_TOK * NE * 4;
  int* idx             = (int*)ws;            ws += (size_t)NE * N_TOK * 4;
  int* cnt             = (int*)ws;            ws += 256;
  __hip_bfloat16* hpool = (__hip_bfloat16*)ws;  // NE*N_TOK*HID*2 = 134 MB

  selector_kernel<<<N_TOK / 16, 256, 0, stream>>>(x, Wsel, bsel, x_bf, sw,
                                                  (float4*)out);
  compact_convert_kernel<<<dim3(16, 16, 17), 1024, 0, stream>>>(
      sw, idx, cnt, W1, W2, W1t, W2t);

  moe_gemm<0><<<dim3(HID / 128, N_TOK / 128, NE), 256, 0, stream>>>(
      x_bf, hpool, W1t, b1, sw, idx, cnt, out);
  moe_gemm<1><<<dim3(DOUT / 128, N_TOK / 128, NE), 256, 0, stream>>>(
      x_bf, hpool, W2t, b2, sw, idx, cnt, out);
}